// Round 7
// baseline (263.342 us; speedup 1.0000x reference)
//
#include <hip/hip_runtime.h>

#define EPSV 1e-5f

// problem sizes
#define NB   8
#define CC   128
#define HH   56
#define WW   56
#define HW   3136      // 56*56
#define NHW  25088     // 8*3136
#define GG   8

// workspace offsets (in floats) — total 13064224 floats ~= 52 MB
// xT ([b][c][w][h]) aliases SV region (dead after K1; sv first written by K5).
// qr path removed entirely: qr is constant along the softmax axis (broadcast
// [:,:,:,None,:]) and softmax(a+c)=softmax(a), so qr and all BN *shifts* of
// qr/kr/qk cancel exactly. Only kr_sc and qk_sc survive.
#define OFF_QKV      0            // [256][NHW]  (o-major; spatial = w*56+h)
#define OFF_SV       6422528      // [128][NHW]  (ch-major, ch = g*16+c; spatial w*56+h)
#define OFF_SVE      9633792      // [128][NHW]
#define OFF_KRB      12845056     // [b][g][w][j] = [8][8][56][56]
#define OFF_QKVSC    13045760     // [256] scale
#define OFF_QKVSH    13046016     // [256] shift
#define OFF_BNPAR    13046272     // [16]: kr_sc[8], qk_sc[8]
#define OFF_BNPAR2   13046288     // [512]: sv_sc[128], sv_sh[128], sve_sc[128], sve_sh[128]
#define OFF_ACCUM    13046816     // [32 x 32]: kr_s, kr_s2, qk_s, qk_s2 (128B-padded lines)
#define OFF_ACCUM2   13047840     // [512 x 32]: (ch*4+{sv_s,sv_s2,sve_s,sve_s2})*32
#define WS_FLOATS    13064224

// padded accumulator slot: one 128B cache line per counter
#define ACC_IDX(u, g) (((u) * 8 + (g)) * 32)

// ---------------------------------------------------------------------------
// K0: transpose x[b][c][h][w] -> xT[b][c][w][h]. One (b,c) plane per block.
// ---------------------------------------------------------------------------
__global__ __launch_bounds__(256) void k0_transpose(
    const float* __restrict__ x, float* __restrict__ xT) {
  __shared__ float t[56][60];
  const int c = blockIdx.x & 127, b = blockIdx.x >> 7;
  const size_t base = ((size_t)b * 128 + c) * HW;
  const int tid = threadIdx.x;
  for (int f = tid; f < 784; f += 256) {
    int e = f * 4;
    int h = e / 56, w = e - h * 56;          // w multiple of 4
    float4 v = *(const float4*)(x + base + e);
    *(float4*)&t[h][w] = v;
  }
  __syncthreads();
  for (int f = tid; f < 784; f += 256) {
    int e = f * 4;
    int w = e / 56, h0 = e - w * 56;         // h0 multiple of 4
    float4 v = make_float4(t[h0][w], t[h0 + 1][w], t[h0 + 2][w], t[h0 + 3][w]);
    *(float4*)(xT + base + w * 56 + h0) = v;
  }
}

// ---------------------------------------------------------------------------
// K1: QKV 1x1-conv GEMM. out[o][p] = sum_k W[o][k] * xT[b][k][s'], s' = w*56+h.
// ---------------------------------------------------------------------------
__global__ __launch_bounds__(256) void k1_qkv(
    const float* __restrict__ x, const float* __restrict__ wq,
    const float* __restrict__ wk, const float* __restrict__ wv,
    float* __restrict__ qkv) {
  __shared__ float Wc[32][132];   // [k][o_local], padded row (528B, float4-aligned)
  __shared__ float Xc[32][64];    // [k][p_local]
  const int p0 = blockIdx.x * 64;
  const int o0 = blockIdx.y * 128;
  const int tid = threadIdx.x;
  const int io = tid & 15, ip = tid >> 4;
  const int bb = p0 / HW;
  const int s0 = p0 - bb * HW;    // 64 | 3136, tile never crosses b

  float acc[8][4];
#pragma unroll
  for (int r = 0; r < 8; ++r)
#pragma unroll
    for (int s = 0; s < 4; ++s) acc[r][s] = 0.f;

  for (int kc = 0; kc < 128; kc += 32) {
    if (kc) __syncthreads();
#pragma unroll
    for (int r = 0; r < 4; ++r) {
      int f = tid + 256 * r;            // 1024 float4 slots
      int ol = f >> 3;
      int kq = (f & 7) * 4;
      int o = o0 + ol;
      const float* wsrc = (o < 64) ? (wq + (size_t)o * 128)
                        : (o < 128) ? (wk + (size_t)(o - 64) * 128)
                                    : (wv + (size_t)(o - 128) * 128);
      float4 w4 = *(const float4*)(wsrc + kc + kq);
      Wc[kq + 0][ol] = w4.x; Wc[kq + 1][ol] = w4.y;
      Wc[kq + 2][ol] = w4.z; Wc[kq + 3][ol] = w4.w;
    }
#pragma unroll
    for (int r = 0; r < 2; ++r) {
      int f = tid + 256 * r;            // 512 float4 slots
      int k = f >> 4;
      int pq = (f & 15) * 4;
      float4 x4 = *(const float4*)(x + (size_t)(bb * 128 + kc + k) * HW + s0 + pq);
      *(float4*)&Xc[k][pq] = x4;
    }
    __syncthreads();
#pragma unroll
    for (int k = 0; k < 32; ++k) {
      float4 xv = *(const float4*)&Xc[k][ip * 4];
      float4 wa = *(const float4*)&Wc[k][io * 8];
      float4 wb = *(const float4*)&Wc[k][io * 8 + 4];
      float wr[8] = {wa.x, wa.y, wa.z, wa.w, wb.x, wb.y, wb.z, wb.w};
      float xr[4] = {xv.x, xv.y, xv.z, xv.w};
#pragma unroll
      for (int r = 0; r < 8; ++r)
#pragma unroll
        for (int s = 0; s < 4; ++s)
          acc[r][s] = fmaf(wr[r], xr[s], acc[r][s]);
    }
  }
#pragma unroll
  for (int r = 0; r < 8; ++r) {
    float4 o4 = make_float4(acc[r][0], acc[r][1], acc[r][2], acc[r][3]);
    *(float4*)(qkv + (size_t)(o0 + io * 8 + r) * NHW + p0 + ip * 4) = o4;
  }
}

// ---------------------------------------------------------------------------
// K2: per-channel BN stats for q/k/v -> scale/shift. One block per channel.
// ---------------------------------------------------------------------------
__global__ __launch_bounds__(256) void k2_stats(
    const float* __restrict__ qkv,
    const float* __restrict__ g_q, const float* __restrict__ b_q,
    const float* __restrict__ g_k, const float* __restrict__ b_k,
    const float* __restrict__ g_v, const float* __restrict__ b_v,
    float* __restrict__ sc_out, float* __restrict__ sh_out) {
  const int o = blockIdx.x;
  const float4* p = (const float4*)(qkv + (size_t)o * NHW);
  float s = 0.f, s2 = 0.f;
  for (int f = threadIdx.x; f < NHW / 4; f += 256) {
    float4 v = p[f];
    s  += v.x + v.y + v.z + v.w;
    s2 += v.x * v.x + v.y * v.y + v.z * v.z + v.w * v.w;
  }
#pragma unroll
  for (int off = 32; off > 0; off >>= 1) {
    s  += __shfl_down(s, off);
    s2 += __shfl_down(s2, off);
  }
  __shared__ float ls[8];
  int wv_ = threadIdx.x >> 6, ln = threadIdx.x & 63;
  if (ln == 0) { ls[wv_] = s; ls[4 + wv_] = s2; }
  __syncthreads();
  if (threadIdx.x == 0) {
    s  = ls[0] + ls[1] + ls[2] + ls[3];
    s2 = ls[4] + ls[5] + ls[6] + ls[7];
    float mean = s / (float)NHW;
    float var  = s2 / (float)NHW - mean * mean;
    float g, b;
    if (o < 64)       { g = g_q[o];       b = b_q[o]; }
    else if (o < 128) { g = g_k[o - 64];  b = b_k[o - 64]; }
    else              { g = g_v[o - 128]; b = b_v[o - 128]; }
    float sc = g * rsqrtf(var + EPSV);
    sc_out[o] = sc;
    sh_out[o] = b - mean * sc;
  }
}

// ---------------------------------------------------------------------------
// K3: kr base (raw, pre-BN) + kr/qk sum/sumsq per group (qr path removed —
// it cancels in softmax). Padded-line atomics.
// ---------------------------------------------------------------------------
__global__ __launch_bounds__(256) void k3_scores(
    const float* __restrict__ qkv,
    const float* __restrict__ qsc, const float* __restrict__ qsh,
    const float* __restrict__ k_rel,
    float* __restrict__ krb, float* __restrict__ accum) {
  __shared__ float qn[8][4][56];   // [c][wl][h]
  __shared__ float kn[8][4][56];
  __shared__ float red[4][4];
  const int w0 = blockIdx.x * 4, g = blockIdx.y, b = blockIdx.z;
  const int tid = threadIdx.x;

  for (int f = tid; f < 896; f += 256) {
    int isK = f >= 448;
    int idx = f - 448 * isK;
    int c = idx / 56, r = idx - c * 56;
    int wl = r / 14, hq = (r - wl * 14) * 4;
    int o = g * 8 + c + 64 * isK;
    float4 v = *(const float4*)(qkv + (size_t)o * NHW + b * HW + (w0 + wl) * 56 + hq);
    float sc = qsc[o], sh = qsh[o];
    float4 n = make_float4(fmaf(v.x, sc, sh), fmaf(v.y, sc, sh),
                           fmaf(v.z, sc, sh), fmaf(v.w, sc, sh));
    if (isK) *(float4*)&kn[c][wl][hq] = n;
    else     *(float4*)&qn[c][wl][hq] = n;
  }
  __syncthreads();

  float vkr = 0.f, vkr2 = 0.f, vqk = 0.f, vqk2 = 0.f;
  if (tid < 224) {
    const int i = tid % 56, wl = tid / 56;
    float qreg[8];
#pragma unroll
    for (int c = 0; c < 8; ++c) qreg[c] = qn[c][wl][i];
    float krv = 0.f;
#pragma unroll
    for (int c = 0; c < 8; ++c)
      krv = fmaf(kn[c][wl][i], k_rel[c * 56 + i], krv);
    size_t bo = ((size_t)(b * 8 + g) * 56 + w0 + wl) * 56 + i;  // [b][g][w][j]
    krb[bo] = krv;
    vkr = krv; vkr2 = krv * krv;
#pragma unroll
    for (int jq = 0; jq < 14; ++jq) {
      float s0 = 0.f, s1 = 0.f, s2 = 0.f, s3 = 0.f;
#pragma unroll
      for (int c = 0; c < 8; ++c) {
        const float* kp = &kn[c][wl][jq * 4];
        float qc = qreg[c];
        s0 = fmaf(qc, kp[0], s0); s1 = fmaf(qc, kp[1], s1);
        s2 = fmaf(qc, kp[2], s2); s3 = fmaf(qc, kp[3], s3);
      }
      vqk  += s0 + s1 + s2 + s3;
      vqk2 += s0 * s0 + s1 * s1 + s2 * s2 + s3 * s3;
    }
  }
  float vals[4] = {vkr, vkr2, vqk, vqk2};
#pragma unroll
  for (int u = 0; u < 4; ++u)
#pragma unroll
    for (int off = 32; off > 0; off >>= 1) vals[u] += __shfl_down(vals[u], off);
  int wv_ = tid >> 6, ln = tid & 63;
  if (ln == 0)
#pragma unroll
    for (int u = 0; u < 4; ++u) red[wv_][u] = vals[u];
  __syncthreads();
  if (tid == 0) {
#pragma unroll
    for (int u = 0; u < 4; ++u)
      atomicAdd(&accum[ACC_IDX(u, g)], red[0][u] + red[1][u] + red[2][u] + red[3][u]);
  }
}

// ---------------------------------------------------------------------------
// K4: fold stats -> per-group scales (shifts cancel in softmax).
// ---------------------------------------------------------------------------
__global__ void k4_bn(
    const float* __restrict__ accum,
    const float* __restrict__ g_kr, const float* __restrict__ g_qk,
    float* __restrict__ bnpar) {
  int g = threadIdx.x;
  if (g >= 8) return;
  const float inv1 = 1.f / 25088.f;      // kr count (N*H*W)
  const float inv2 = 1.f / 1404928.f;    // qk count (N*H*H*W)
  float m, v;
  m = accum[ACC_IDX(0, g)] * inv1; v = accum[ACC_IDX(1, g)] * inv1 - m * m;
  bnpar[g]     = g_kr[g] * rsqrtf(v + EPSV);
  m = accum[ACC_IDX(2, g)] * inv2; v = accum[ACC_IDX(3, g)] * inv2 - m * m;
  bnpar[8 + g] = g_qk[g] * rsqrtf(v + EPSV);
}

// ---------------------------------------------------------------------------
// K5: attention + fused sv/sve BN-stats reduction (butterfly-shuffle + LDS
// fold + 64 padded-line atomics per block). Block = (w-tile, g, b).
// ---------------------------------------------------------------------------
__global__ __launch_bounds__(256) void k5_attn(
    const float* __restrict__ qkv,
    const float* __restrict__ qsc, const float* __restrict__ qsh,
    const float* __restrict__ krb, const float* __restrict__ bnpar,
    const float* __restrict__ v_rel,
    float* __restrict__ sv_ws, float* __restrict__ sve_ws,
    float* __restrict__ accum2) {
  __shared__ float qn[8][4][56];    // [c][wl][h]
  __shared__ float kn[8][4][56];
  __shared__ float vn[16][4][56];
  __shared__ float krn[4][56];
  __shared__ float vr[16][56];
  __shared__ float wred[4][16][4];
  const int w0 = blockIdx.x * 4, g = blockIdx.y, b = blockIdx.z;
  const int tid = threadIdx.x;

  for (int f = tid; f < 1792; f += 256) {
    int c, o; float* dst;
    int idx = f;
    if (f < 448)      { c = idx / 56;                      o = g * 8 + c;         dst = (float*)qn + c * 224; }
    else if (f < 896) { idx = f - 448; c = idx / 56;       o = 64 + g * 8 + c;    dst = (float*)kn + c * 224; }
    else              { idx = f - 896; c = idx / 56;       o = 128 + g * 16 + c;  dst = (float*)vn + c * 224; }
    int r = idx - c * 56;
    int wl = r / 14, hq = (r - wl * 14) * 4;
    float4 v = *(const float4*)(qkv + (size_t)o * NHW + b * HW + (w0 + wl) * 56 + hq);
    float sc = qsc[o], sh = qsh[o];
    float4 n = make_float4(fmaf(v.x, sc, sh), fmaf(v.y, sc, sh),
                           fmaf(v.z, sc, sh), fmaf(v.w, sc, sh));
    *(float4*)(dst + wl * 56 + hq) = n;
  }
  {
    float kr_sc = bnpar[g];
    if (tid < 224) {
      int i = tid % 56, wl = tid / 56;
      size_t bo = ((size_t)(b * 8 + g) * 56 + w0 + wl) * 56 + i;  // [b][g][w][j]
      krn[wl][i] = krb[bo] * kr_sc;    // shift cancels in softmax
    }
  }
  for (int f = tid; f < 896; f += 256) ((float*)vr)[f] = v_rel[f];
  __syncthreads();

  float sv[16], sve[16];
#pragma unroll
  for (int c = 0; c < 16; ++c) { sv[c] = 0.f; sve[c] = 0.f; }
  float inv = 0.f;
  const int i = tid % 56, wl = tid / 56;

  if (tid < 224) {
    float qreg[8];
#pragma unroll
    for (int c = 0; c < 8; ++c) qreg[c] = qn[c][wl][i];
    const float qksc = bnpar[8 + g];

    float srow[56];
    float mx = -3.402823466e38f;
#pragma unroll
    for (int jq = 0; jq < 14; ++jq) {
      float s0 = 0.f, s1 = 0.f, s2 = 0.f, s3 = 0.f;
#pragma unroll
      for (int c = 0; c < 8; ++c) {
        const float* kp = &kn[c][wl][jq * 4];
        float qc = qreg[c];
        s0 = fmaf(qc, kp[0], s0); s1 = fmaf(qc, kp[1], s1);
        s2 = fmaf(qc, kp[2], s2); s3 = fmaf(qc, kp[3], s3);
      }
      const float* krp = &krn[wl][jq * 4];
      s0 = fmaf(qksc, s0, krp[0]);
      s1 = fmaf(qksc, s1, krp[1]);
      s2 = fmaf(qksc, s2, krp[2]);
      s3 = fmaf(qksc, s3, krp[3]);
      srow[jq * 4 + 0] = s0; srow[jq * 4 + 1] = s1;
      srow[jq * 4 + 2] = s2; srow[jq * 4 + 3] = s3;
      mx = fmaxf(mx, fmaxf(fmaxf(s0, s1), fmaxf(s2, s3)));
    }
    float sum = 0.f;
#pragma unroll
    for (int j = 0; j < 56; ++j) {
      float p = expf(srow[j] - mx);
      srow[j] = p;
      sum += p;
    }
    inv = 1.f / sum;

#pragma unroll
    for (int jq = 0; jq < 14; ++jq) {
      float p0 = srow[jq * 4], p1 = srow[jq * 4 + 1];
      float p2 = srow[jq * 4 + 2], p3 = srow[jq * 4 + 3];
#pragma unroll
      for (int c = 0; c < 16; ++c) {
        const float* vp  = &vn[c][wl][jq * 4];
        const float* vrp = &vr[c][jq * 4];
        sv[c]  = fmaf(p0, vp[0],  fmaf(p1, vp[1],  fmaf(p2, vp[2],  fmaf(p3, vp[3],  sv[c]))));
        sve[c] = fmaf(p0, vrp[0], fmaf(p1, vrp[1], fmaf(p2, vrp[2], fmaf(p3, vrp[3], sve[c]))));
      }
    }
  }

  // write final values + reduce per-channel stats (all 64 lanes shuffle;
  // inactive threads contribute zeros)
#pragma unroll
  for (int c = 0; c < 16; ++c) {
    float fv = 0.f, ev = 0.f;
    if (tid < 224) {
      fv = sv[c] * inv; ev = sve[c] * inv;
      size_t base = (size_t)(g * 16 + c) * NHW + b * HW + (w0 + wl) * 56 + i;
      sv_ws[base]  = fv;
      sve_ws[base] = ev;
    }
    float s0 = fv, s1 = fv * fv, s2 = ev, s3 = ev * ev;
#pragma unroll
    for (int off = 32; off > 0; off >>= 1) {
      s0 += __shfl_xor(s0, off); s1 += __shfl_xor(s1, off);
      s2 += __shfl_xor(s2, off); s3 += __shfl_xor(s3, off);
    }
    if ((tid & 63) == 0) {
      int wv_ = tid >> 6;
      wred[wv_][c][0] = s0; wred[wv_][c][1] = s1;
      wred[wv_][c][2] = s2; wred[wv_][c][3] = s3;
    }
  }
  __syncthreads();
  if (tid < 64) {
    int c = tid >> 2, st = tid & 3;
    float v = wred[0][c][st] + wred[1][c][st] + wred[2][c][st] + wred[3][c][st];
    atomicAdd(&accum2[(((g * 16 + c) * 4) + st) * 32], v);
  }
}

// ---------------------------------------------------------------------------
// K6b: fold accumulated sv/sve stats into bnpar2 (tiny).
// ---------------------------------------------------------------------------
__global__ void k6b_fold(
    const float* __restrict__ accum2,
    const float* __restrict__ g_sv, const float* __restrict__ b_sv,
    const float* __restrict__ g_sve, const float* __restrict__ b_sve,
    float* __restrict__ bnpar2) {
  int ch = threadIdx.x;
  if (ch >= 128) return;
  const float invn = 1.f / 25088.f;
  float m, v, sc;
  m = accum2[(ch * 4 + 0) * 32] * invn;
  v = accum2[(ch * 4 + 1) * 32] * invn - m * m;
  sc = g_sv[ch] * rsqrtf(v + EPSV);
  bnpar2[ch] = sc; bnpar2[128 + ch] = b_sv[ch] - m * sc;
  m = accum2[(ch * 4 + 2) * 32] * invn;
  v = accum2[(ch * 4 + 3) * 32] * invn - m * m;
  sc = g_sve[ch] * rsqrtf(v + EPSV);
  bnpar2[256 + ch] = sc; bnpar2[384 + ch] = b_sve[ch] - m * sc;
}

// ---------------------------------------------------------------------------
// K7: fused double-BN + transpose back: out[b][ch][h][w] from
// sv/sve[ch][b][w][h]. One (ch,b) plane per block, LDS-tiled.
// ---------------------------------------------------------------------------
__global__ __launch_bounds__(256) void k7_out(
    const float* __restrict__ sv_ws, const float* __restrict__ sve_ws,
    const float* __restrict__ bnpar2, float* __restrict__ out) {
  __shared__ float t[56][60];
  const int ch = blockIdx.x & 127, b = blockIdx.x >> 7;
  const int tid = threadIdx.x;
  const float asc = bnpar2[ch], ash = bnpar2[128 + ch];
  const float esc = bnpar2[256 + ch], esh = bnpar2[384 + ch];
  const size_t pin = ((size_t)ch * NB + b) * HW;
  for (int f = tid; f < 784; f += 256) {
    int e = f * 4;
    int w = e / 56, h = e - w * 56;          // h multiple of 4
    float4 a  = *(const float4*)(sv_ws + pin + e);
    float4 c4 = *(const float4*)(sve_ws + pin + e);
    float4 o4;
    o4.x = fmaf(a.x, asc, ash) + fmaf(c4.x, esc, esh);
    o4.y = fmaf(a.y, asc, ash) + fmaf(c4.y, esc, esh);
    o4.z = fmaf(a.z, asc, ash) + fmaf(c4.z, esc, esh);
    o4.w = fmaf(a.w, asc, ash) + fmaf(c4.w, esc, esh);
    *(float4*)&t[w][h] = o4;
  }
  __syncthreads();
  const size_t pout = ((size_t)b * 128 + ch) * HW;
  for (int f = tid; f < 784; f += 256) {
    int e = f * 4;
    int h = e / 56, w0 = e - h * 56;         // w0 multiple of 4
    float4 o4 = make_float4(t[w0][h], t[w0 + 1][h], t[w0 + 2][h], t[w0 + 3][h]);
    *(float4*)(out + pout + h * 56 + w0) = o4;
  }
}

// ---------------------------------------------------------------------------
extern "C" void kernel_launch(void* const* d_in, const int* in_sizes, int n_in,
                              void* d_out, int out_size, void* d_ws, size_t ws_size,
                              hipStream_t stream) {
  (void)in_sizes; (void)n_in; (void)out_size;
  if (ws_size < (size_t)WS_FLOATS * sizeof(float)) return;  // diagnostic guard

  const float* x     = (const float*)d_in[0];
  const float* wq    = (const float*)d_in[1];
  const float* wk    = (const float*)d_in[2];
  const float* wv    = (const float*)d_in[3];
  const float* k_rel = (const float*)d_in[5];
  const float* v_rel = (const float*)d_in[6];
  const float* g_q   = (const float*)d_in[7];
  const float* b_q   = (const float*)d_in[8];
  const float* g_k   = (const float*)d_in[9];
  const float* b_k   = (const float*)d_in[10];
  const float* g_v   = (const float*)d_in[11];
  const float* b_v   = (const float*)d_in[12];
  const float* g_kr  = (const float*)d_in[15];
  const float* g_qk  = (const float*)d_in[17];
  const float* g_sv  = (const float*)d_in[19];
  const float* b_sv  = (const float*)d_in[20];
  const float* g_sve = (const float*)d_in[21];
  const float* b_sve = (const float*)d_in[22];
  // q_rel (4), b_qr(14), g_qr(13), b_kr(16), b_qk(18) unused: they cancel in softmax.

  float* ws     = (float*)d_ws;
  float* qkv    = ws + OFF_QKV;
  float* sv_ws  = ws + OFF_SV;
  float* sve_ws = ws + OFF_SVE;
  float* xT     = ws + OFF_SV;      // aliases SV region (dead after K1)
  float* krb    = ws + OFF_KRB;
  float* qkvsc  = ws + OFF_QKVSC;
  float* qkvsh  = ws + OFF_QKVSH;
  float* bnpar  = ws + OFF_BNPAR;
  float* bnpar2 = ws + OFF_BNPAR2;
  float* accum  = ws + OFF_ACCUM;
  float* accum2 = ws + OFF_ACCUM2;

  // zero both accumulator regions (contiguous)
  hipMemsetAsync(accum, 0, (WS_FLOATS - OFF_ACCUM) * sizeof(float), stream);

  k0_transpose<<<1024, 256, 0, stream>>>(x, xT);
  k1_qkv<<<dim3(392, 2), 256, 0, stream>>>(xT, wq, wk, wv, qkv);
  k2_stats<<<256, 256, 0, stream>>>(qkv, g_q, b_q, g_k, b_k, g_v, b_v, qkvsc, qkvsh);
  k3_scores<<<dim3(14, 8, 8), 256, 0, stream>>>(qkv, qkvsc, qkvsh, k_rel, krb, accum);
  k4_bn<<<1, 64, 0, stream>>>(accum, g_kr, g_qk, bnpar);
  k5_attn<<<dim3(14, 8, 8), 256, 0, stream>>>(qkv, qkvsc, qkvsh, krb, bnpar, v_rel, sv_ws, sve_ws, accum2);
  k6b_fold<<<1, 128, 0, stream>>>(accum2, g_sv, b_sv, g_sve, b_sve, bnpar2);
  k7_out<<<1024, 256, 0, stream>>>(sv_ws, sve_ws, bnpar2, (float*)d_out);
}

// Round 10
// 209.779 us; speedup vs baseline: 1.2553x; 1.2553x over previous
//
#include <hip/hip_runtime.h>

#define EPSV 1e-5f

// problem sizes
#define NB   8
#define CC   128
#define HH   56
#define WW   56
#define HW   3136      // 56*56
#define NHW  25088     // 8*3136
#define GG   8

// workspace offsets (in floats)
// xT ([b][c][w][h]) aliases SV region (dead after K1; sv first written by K5).
// qr path removed: qr is constant along the softmax axis and softmax(a+c)=
// softmax(a), so qr and the BN shifts of qr/kr/qk cancel exactly.
#define OFF_QKV      0            // [256][NHW]  (o-major; spatial = w*56+h)
#define OFF_SV       6422528      // [128][NHW]  (ch-major, ch = g*16+c; spatial w*56+h)
#define OFF_SVE      9633792      // [128][NHW]
#define OFF_KRB      12845056     // [b][g][w][j] = [8][8][56][56]
#define OFF_QKVSC    13045760     // [256] scale
#define OFF_QKVSH    13046016     // [256] shift
#define OFF_BNPAR    13046272     // [16]: kr_sc[8], qk_sc[8]
#define OFF_BNPAR2   13046288     // [512]: sv_sc[128], sv_sh[128], sve_sc[128], sve_sh[128]
#define OFF_ACCUM    13046816     // [32 x 32]: kr_s, kr_s2, qk_s, qk_s2 (128B-padded lines)
#define WS_FLOATS    13047840

// padded accumulator slot: one 128B cache line per counter
#define ACC_IDX(u, g) (((u) * 8 + (g)) * 32)

// ---------------------------------------------------------------------------
// K0: transpose x[b][c][h][w] -> xT[b][c][w][h]. One (b,c) plane per block.
// ---------------------------------------------------------------------------
__global__ __launch_bounds__(256) void k0_transpose(
    const float* __restrict__ x, float* __restrict__ xT) {
  __shared__ float t[56][60];
  const int c = blockIdx.x & 127, b = blockIdx.x >> 7;
  const size_t base = ((size_t)b * 128 + c) * HW;
  const int tid = threadIdx.x;
  for (int f = tid; f < 784; f += 256) {
    int e = f * 4;
    int h = e / 56, w = e - h * 56;          // w multiple of 4
    float4 v = *(const float4*)(x + base + e);
    *(float4*)&t[h][w] = v;
  }
  __syncthreads();
  for (int f = tid; f < 784; f += 256) {
    int e = f * 4;
    int w = e / 56, h0 = e - w * 56;         // h0 multiple of 4
    float4 v = make_float4(t[h0][w], t[h0 + 1][w], t[h0 + 2][w], t[h0 + 3][w]);
    *(float4*)(xT + base + w * 56 + h0) = v;
  }
}

// ---------------------------------------------------------------------------
// K1: QKV 1x1-conv GEMM. out[o][p] = sum_k W[o][k] * xT[b][k][s'], s' = w*56+h.
// ---------------------------------------------------------------------------
__global__ __launch_bounds__(256) void k1_qkv(
    const float* __restrict__ x, const float* __restrict__ wq,
    const float* __restrict__ wk, const float* __restrict__ wv,
    float* __restrict__ qkv) {
  __shared__ float Wc[32][132];   // [k][o_local], padded row (528B, float4-aligned)
  __shared__ float Xc[32][64];    // [k][p_local]
  const int p0 = blockIdx.x * 64;
  const int o0 = blockIdx.y * 128;
  const int tid = threadIdx.x;
  const int io = tid & 15, ip = tid >> 4;
  const int bb = p0 / HW;
  const int s0 = p0 - bb * HW;    // 64 | 3136, tile never crosses b

  float acc[8][4];
#pragma unroll
  for (int r = 0; r < 8; ++r)
#pragma unroll
    for (int s = 0; s < 4; ++s) acc[r][s] = 0.f;

  for (int kc = 0; kc < 128; kc += 32) {
    if (kc) __syncthreads();
#pragma unroll
    for (int r = 0; r < 4; ++r) {
      int f = tid + 256 * r;            // 1024 float4 slots
      int ol = f >> 3;
      int kq = (f & 7) * 4;
      int o = o0 + ol;
      const float* wsrc = (o < 64) ? (wq + (size_t)o * 128)
                        : (o < 128) ? (wk + (size_t)(o - 64) * 128)
                                    : (wv + (size_t)(o - 128) * 128);
      float4 w4 = *(const float4*)(wsrc + kc + kq);
      Wc[kq + 0][ol] = w4.x; Wc[kq + 1][ol] = w4.y;
      Wc[kq + 2][ol] = w4.z; Wc[kq + 3][ol] = w4.w;
    }
#pragma unroll
    for (int r = 0; r < 2; ++r) {
      int f = tid + 256 * r;            // 512 float4 slots
      int k = f >> 4;
      int pq = (f & 15) * 4;
      float4 x4 = *(const float4*)(x + (size_t)(bb * 128 + kc + k) * HW + s0 + pq);
      *(float4*)&Xc[k][pq] = x4;
    }
    __syncthreads();
#pragma unroll
    for (int k = 0; k < 32; ++k) {
      float4 xv = *(const float4*)&Xc[k][ip * 4];
      float4 wa = *(const float4*)&Wc[k][io * 8];
      float4 wb = *(const float4*)&Wc[k][io * 8 + 4];
      float wr[8] = {wa.x, wa.y, wa.z, wa.w, wb.x, wb.y, wb.z, wb.w};
      float xr[4] = {xv.x, xv.y, xv.z, xv.w};
#pragma unroll
      for (int r = 0; r < 8; ++r)
#pragma unroll
        for (int s = 0; s < 4; ++s)
          acc[r][s] = fmaf(wr[r], xr[s], acc[r][s]);
    }
  }
#pragma unroll
  for (int r = 0; r < 8; ++r) {
    float4 o4 = make_float4(acc[r][0], acc[r][1], acc[r][2], acc[r][3]);
    *(float4*)(qkv + (size_t)(o0 + io * 8 + r) * NHW + p0 + ip * 4) = o4;
  }
}

// ---------------------------------------------------------------------------
// K2: per-channel BN stats for q/k/v -> scale/shift. One block per channel.
// ---------------------------------------------------------------------------
__global__ __launch_bounds__(256) void k2_stats(
    const float* __restrict__ qkv,
    const float* __restrict__ g_q, const float* __restrict__ b_q,
    const float* __restrict__ g_k, const float* __restrict__ b_k,
    const float* __restrict__ g_v, const float* __restrict__ b_v,
    float* __restrict__ sc_out, float* __restrict__ sh_out) {
  const int o = blockIdx.x;
  const float4* p = (const float4*)(qkv + (size_t)o * NHW);
  float s = 0.f, s2 = 0.f;
  for (int f = threadIdx.x; f < NHW / 4; f += 256) {
    float4 v = p[f];
    s  += v.x + v.y + v.z + v.w;
    s2 += v.x * v.x + v.y * v.y + v.z * v.z + v.w * v.w;
  }
#pragma unroll
  for (int off = 32; off > 0; off >>= 1) {
    s  += __shfl_down(s, off);
    s2 += __shfl_down(s2, off);
  }
  __shared__ float ls[8];
  int wv_ = threadIdx.x >> 6, ln = threadIdx.x & 63;
  if (ln == 0) { ls[wv_] = s; ls[4 + wv_] = s2; }
  __syncthreads();
  if (threadIdx.x == 0) {
    s  = ls[0] + ls[1] + ls[2] + ls[3];
    s2 = ls[4] + ls[5] + ls[6] + ls[7];
    float mean = s / (float)NHW;
    float var  = s2 / (float)NHW - mean * mean;
    float g, b;
    if (o < 64)       { g = g_q[o];       b = b_q[o]; }
    else if (o < 128) { g = g_k[o - 64];  b = b_k[o - 64]; }
    else              { g = g_v[o - 128]; b = b_v[o - 128]; }
    float sc = g * rsqrtf(var + EPSV);
    sc_out[o] = sc;
    sh_out[o] = b - mean * sc;
  }
}

// ---------------------------------------------------------------------------
// K3: kr base (raw, pre-BN) + kr/qk sum/sumsq per group. Padded-line atomics.
// ---------------------------------------------------------------------------
__global__ __launch_bounds__(256) void k3_scores(
    const float* __restrict__ qkv,
    const float* __restrict__ qsc, const float* __restrict__ qsh,
    const float* __restrict__ k_rel,
    float* __restrict__ krb, float* __restrict__ accum) {
  __shared__ float qn[8][4][56];   // [c][wl][h]
  __shared__ float kn[8][4][56];
  __shared__ float red[4][4];
  const int w0 = blockIdx.x * 4, g = blockIdx.y, b = blockIdx.z;
  const int tid = threadIdx.x;

  for (int f = tid; f < 896; f += 256) {
    int isK = f >= 448;
    int idx = f - 448 * isK;
    int c = idx / 56, r = idx - c * 56;
    int wl = r / 14, hq = (r - wl * 14) * 4;
    int o = g * 8 + c + 64 * isK;
    float4 v = *(const float4*)(qkv + (size_t)o * NHW + b * HW + (w0 + wl) * 56 + hq);
    float sc = qsc[o], sh = qsh[o];
    float4 n = make_float4(fmaf(v.x, sc, sh), fmaf(v.y, sc, sh),
                           fmaf(v.z, sc, sh), fmaf(v.w, sc, sh));
    if (isK) *(float4*)&kn[c][wl][hq] = n;
    else     *(float4*)&qn[c][wl][hq] = n;
  }
  __syncthreads();

  float vkr = 0.f, vkr2 = 0.f, vqk = 0.f, vqk2 = 0.f;
  if (tid < 224) {
    const int i = tid % 56, wl = tid / 56;
    float qreg[8];
#pragma unroll
    for (int c = 0; c < 8; ++c) qreg[c] = qn[c][wl][i];
    float krv = 0.f;
#pragma unroll
    for (int c = 0; c < 8; ++c)
      krv = fmaf(kn[c][wl][i], k_rel[c * 56 + i], krv);
    size_t bo = ((size_t)(b * 8 + g) * 56 + w0 + wl) * 56 + i;  // [b][g][w][j]
    krb[bo] = krv;
    vkr = krv; vkr2 = krv * krv;
#pragma unroll
    for (int jq = 0; jq < 14; ++jq) {
      float s0 = 0.f, s1 = 0.f, s2 = 0.f, s3 = 0.f;
#pragma unroll
      for (int c = 0; c < 8; ++c) {
        const float* kp = &kn[c][wl][jq * 4];
        float qc = qreg[c];
        s0 = fmaf(qc, kp[0], s0); s1 = fmaf(qc, kp[1], s1);
        s2 = fmaf(qc, kp[2], s2); s3 = fmaf(qc, kp[3], s3);
      }
      vqk  += s0 + s1 + s2 + s3;
      vqk2 += s0 * s0 + s1 * s1 + s2 * s2 + s3 * s3;
    }
  }
  float vals[4] = {vkr, vkr2, vqk, vqk2};
#pragma unroll
  for (int u = 0; u < 4; ++u)
#pragma unroll
    for (int off = 32; off > 0; off >>= 1) vals[u] += __shfl_down(vals[u], off);
  int wv_ = tid >> 6, ln = tid & 63;
  if (ln == 0)
#pragma unroll
    for (int u = 0; u < 4; ++u) red[wv_][u] = vals[u];
  __syncthreads();
  if (tid == 0) {
#pragma unroll
    for (int u = 0; u < 4; ++u)
      atomicAdd(&accum[ACC_IDX(u, g)], red[0][u] + red[1][u] + red[2][u] + red[3][u]);
  }
}

// ---------------------------------------------------------------------------
// K4: fold stats -> per-group scales (shifts cancel in softmax).
// ---------------------------------------------------------------------------
__global__ void k4_bn(
    const float* __restrict__ accum,
    const float* __restrict__ g_kr, const float* __restrict__ g_qk,
    float* __restrict__ bnpar) {
  int g = threadIdx.x;
  if (g >= 8) return;
  const float inv1 = 1.f / 25088.f;      // kr count (N*H*W)
  const float inv2 = 1.f / 1404928.f;    // qk count (N*H*H*W)
  float m, v;
  m = accum[ACC_IDX(0, g)] * inv1; v = accum[ACC_IDX(1, g)] * inv1 - m * m;
  bnpar[g]     = g_kr[g] * rsqrtf(v + EPSV);
  m = accum[ACC_IDX(2, g)] * inv2; v = accum[ACC_IDX(3, g)] * inv2 - m * m;
  bnpar[8 + g] = g_qk[g] * rsqrtf(v + EPSV);
}

// ---------------------------------------------------------------------------
// K5: attention. Block = (w-tile, g, b). Thread (i, wl) owns one softmax row.
// All work inside if(tid<224) — keeps register lifetimes short (R7 lesson:
// fusing the stats reduction here raised VGPR 56->132, occupancy 30->9.6%).
// ---------------------------------------------------------------------------
__global__ __launch_bounds__(256) void k5_attn(
    const float* __restrict__ qkv,
    const float* __restrict__ qsc, const float* __restrict__ qsh,
    const float* __restrict__ krb, const float* __restrict__ bnpar,
    const float* __restrict__ v_rel,
    float* __restrict__ sv_ws, float* __restrict__ sve_ws) {
  __shared__ float qn[8][4][56];    // [c][wl][h]
  __shared__ float kn[8][4][56];
  __shared__ float vn[16][4][56];
  __shared__ float krn[4][56];
  __shared__ float vr[16][56];
  const int w0 = blockIdx.x * 4, g = blockIdx.y, b = blockIdx.z;
  const int tid = threadIdx.x;

  for (int f = tid; f < 1792; f += 256) {
    int c, o; float* dst;
    int idx = f;
    if (f < 448)      { c = idx / 56;                      o = g * 8 + c;         dst = (float*)qn + c * 224; }
    else if (f < 896) { idx = f - 448; c = idx / 56;       o = 64 + g * 8 + c;    dst = (float*)kn + c * 224; }
    else              { idx = f - 896; c = idx / 56;       o = 128 + g * 16 + c;  dst = (float*)vn + c * 224; }
    int r = idx - c * 56;
    int wl = r / 14, hq = (r - wl * 14) * 4;
    float4 v = *(const float4*)(qkv + (size_t)o * NHW + b * HW + (w0 + wl) * 56 + hq);
    float sc = qsc[o], sh = qsh[o];
    float4 n = make_float4(fmaf(v.x, sc, sh), fmaf(v.y, sc, sh),
                           fmaf(v.z, sc, sh), fmaf(v.w, sc, sh));
    *(float4*)(dst + wl * 56 + hq) = n;
  }
  {
    float kr_sc = bnpar[g];
    if (tid < 224) {
      int i = tid % 56, wl = tid / 56;
      size_t bo = ((size_t)(b * 8 + g) * 56 + w0 + wl) * 56 + i;  // [b][g][w][j]
      krn[wl][i] = krb[bo] * kr_sc;    // shift cancels in softmax
    }
  }
  for (int f = tid; f < 896; f += 256) ((float*)vr)[f] = v_rel[f];
  __syncthreads();

  if (tid < 224) {
    const int i = tid % 56, wl = tid / 56;
    float qreg[8];
#pragma unroll
    for (int c = 0; c < 8; ++c) qreg[c] = qn[c][wl][i];
    const float qksc = bnpar[8 + g];

    float srow[56];
    float mx = -3.402823466e38f;
#pragma unroll
    for (int jq = 0; jq < 14; ++jq) {
      float s0 = 0.f, s1 = 0.f, s2 = 0.f, s3 = 0.f;
#pragma unroll
      for (int c = 0; c < 8; ++c) {
        const float* kp = &kn[c][wl][jq * 4];
        float qc = qreg[c];
        s0 = fmaf(qc, kp[0], s0); s1 = fmaf(qc, kp[1], s1);
        s2 = fmaf(qc, kp[2], s2); s3 = fmaf(qc, kp[3], s3);
      }
      const float* krp = &krn[wl][jq * 4];
      s0 = fmaf(qksc, s0, krp[0]);
      s1 = fmaf(qksc, s1, krp[1]);
      s2 = fmaf(qksc, s2, krp[2]);
      s3 = fmaf(qksc, s3, krp[3]);
      srow[jq * 4 + 0] = s0; srow[jq * 4 + 1] = s1;
      srow[jq * 4 + 2] = s2; srow[jq * 4 + 3] = s3;
      mx = fmaxf(mx, fmaxf(fmaxf(s0, s1), fmaxf(s2, s3)));
    }
    float sum = 0.f;
#pragma unroll
    for (int j = 0; j < 56; ++j) {
      float p = expf(srow[j] - mx);
      srow[j] = p;
      sum += p;
    }
    float inv = 1.f / sum;

    float sv[16], sve[16];
#pragma unroll
    for (int c = 0; c < 16; ++c) { sv[c] = 0.f; sve[c] = 0.f; }
#pragma unroll
    for (int jq = 0; jq < 14; ++jq) {
      float p0 = srow[jq * 4], p1 = srow[jq * 4 + 1];
      float p2 = srow[jq * 4 + 2], p3 = srow[jq * 4 + 3];
#pragma unroll
      for (int c = 0; c < 16; ++c) {
        const float* vp  = &vn[c][wl][jq * 4];
        const float* vrp = &vr[c][jq * 4];
        sv[c]  = fmaf(p0, vp[0],  fmaf(p1, vp[1],  fmaf(p2, vp[2],  fmaf(p3, vp[3],  sv[c]))));
        sve[c] = fmaf(p0, vrp[0], fmaf(p1, vrp[1], fmaf(p2, vrp[2], fmaf(p3, vrp[3], sve[c]))));
      }
    }
#pragma unroll
    for (int c = 0; c < 16; ++c) {
      size_t base = (size_t)(g * 16 + c) * NHW + b * HW + (w0 + wl) * 56 + i;
      sv_ws[base]  = sv[c]  * inv;   // contiguous across consecutive tid (i)
      sve_ws[base] = sve[c] * inv;
    }
  }
}

// ---------------------------------------------------------------------------
// K6: per-channel BN stats for sv (blocks 0-127) and sve (blocks 128-255),
// folded directly into bnpar2.
// ---------------------------------------------------------------------------
__global__ __launch_bounds__(256) void k6_stats2(
    const float* __restrict__ sv_ws, const float* __restrict__ sve_ws,
    const float* __restrict__ g_sv, const float* __restrict__ b_sv,
    const float* __restrict__ g_sve, const float* __restrict__ b_sve,
    float* __restrict__ bnpar2) {
  const int cb = blockIdx.x;
  const int ch = cb & 127;
  const float* src = (cb < 128) ? sv_ws : sve_ws;
  const float4* p = (const float4*)(src + (size_t)ch * NHW);
  float s = 0.f, s2 = 0.f;
  for (int f = threadIdx.x; f < NHW / 4; f += 256) {
    float4 v = p[f];
    s  += v.x + v.y + v.z + v.w;
    s2 += v.x * v.x + v.y * v.y + v.z * v.z + v.w * v.w;
  }
#pragma unroll
  for (int off = 32; off > 0; off >>= 1) {
    s  += __shfl_down(s, off);
    s2 += __shfl_down(s2, off);
  }
  __shared__ float ls[8];
  int wv_ = threadIdx.x >> 6, ln = threadIdx.x & 63;
  if (ln == 0) { ls[wv_] = s; ls[4 + wv_] = s2; }
  __syncthreads();
  if (threadIdx.x == 0) {
    s  = ls[0] + ls[1] + ls[2] + ls[3];
    s2 = ls[4] + ls[5] + ls[6] + ls[7];
    float m = s / (float)NHW;
    float var = s2 / (float)NHW - m * m;
    float gm = (cb < 128) ? g_sv[ch] : g_sve[ch];
    float bt = (cb < 128) ? b_sv[ch] : b_sve[ch];
    float sc = gm * rsqrtf(var + EPSV);
    int off = (cb < 128) ? 0 : 256;
    bnpar2[off + ch] = sc;
    bnpar2[off + 128 + ch] = bt - m * sc;
  }
}

// ---------------------------------------------------------------------------
// K7: fused double-BN + transpose back: out[b][ch][h][w] from
// sv/sve[ch][b][w][h]. One (ch,b) plane per block, LDS-tiled.
// ---------------------------------------------------------------------------
__global__ __launch_bounds__(256) void k7_out(
    const float* __restrict__ sv_ws, const float* __restrict__ sve_ws,
    const float* __restrict__ bnpar2, float* __restrict__ out) {
  __shared__ float t[56][60];
  const int ch = blockIdx.x & 127, b = blockIdx.x >> 7;
  const int tid = threadIdx.x;
  const float asc = bnpar2[ch], ash = bnpar2[128 + ch];
  const float esc = bnpar2[256 + ch], esh = bnpar2[384 + ch];
  const size_t pin = ((size_t)ch * NB + b) * HW;
  for (int f = tid; f < 784; f += 256) {
    int e = f * 4;
    int w = e / 56, h = e - w * 56;          // h multiple of 4
    float4 a  = *(const float4*)(sv_ws + pin + e);
    float4 c4 = *(const float4*)(sve_ws + pin + e);
    float4 o4;
    o4.x = fmaf(a.x, asc, ash) + fmaf(c4.x, esc, esh);
    o4.y = fmaf(a.y, asc, ash) + fmaf(c4.y, esc, esh);
    o4.z = fmaf(a.z, asc, ash) + fmaf(c4.z, esc, esh);
    o4.w = fmaf(a.w, asc, ash) + fmaf(c4.w, esc, esh);
    *(float4*)&t[w][h] = o4;
  }
  __syncthreads();
  const size_t pout = ((size_t)b * 128 + ch) * HW;
  for (int f = tid; f < 784; f += 256) {
    int e = f * 4;
    int h = e / 56, w0 = e - h * 56;         // w0 multiple of 4
    float4 o4 = make_float4(t[w0][h], t[w0 + 1][h], t[w0 + 2][h], t[w0 + 3][h]);
    *(float4*)(out + pout + h * 56 + w0) = o4;
  }
}

// ---------------------------------------------------------------------------
extern "C" void kernel_launch(void* const* d_in, const int* in_sizes, int n_in,
                              void* d_out, int out_size, void* d_ws, size_t ws_size,
                              hipStream_t stream) {
  (void)in_sizes; (void)n_in; (void)out_size;
  if (ws_size < (size_t)WS_FLOATS * sizeof(float)) return;  // diagnostic guard

  const float* x     = (const float*)d_in[0];
  const float* wq    = (const float*)d_in[1];
  const float* wk    = (const float*)d_in[2];
  const float* wv    = (const float*)d_in[3];
  const float* k_rel = (const float*)d_in[5];
  const float* v_rel = (const float*)d_in[6];
  const float* g_q   = (const float*)d_in[7];
  const float* b_q   = (const float*)d_in[8];
  const float* g_k   = (const float*)d_in[9];
  const float* b_k   = (const float*)d_in[10];
  const float* g_v   = (const float*)d_in[11];
  const float* b_v   = (const float*)d_in[12];
  const float* g_kr  = (const float*)d_in[15];
  const float* g_qk  = (const float*)d_in[17];
  const float* g_sv  = (const float*)d_in[19];
  const float* b_sv  = (const float*)d_in[20];
  const float* g_sve = (const float*)d_in[21];
  const float* b_sve = (const float*)d_in[22];
  // q_rel(4), g_qr(13), b_qr(14), b_kr(16), b_qk(18) unused: cancel in softmax.

  float* ws     = (float*)d_ws;
  float* qkv    = ws + OFF_QKV;
  float* sv_ws  = ws + OFF_SV;
  float* sve_ws = ws + OFF_SVE;
  float* xT     = ws + OFF_SV;      // aliases SV region (dead after K1)
  float* krb    = ws + OFF_KRB;
  float* qkvsc  = ws + OFF_QKVSC;
  float* qkvsh  = ws + OFF_QKVSH;
  float* bnpar  = ws + OFF_BNPAR;
  float* bnpar2 = ws + OFF_BNPAR2;
  float* accum  = ws + OFF_ACCUM;

  hipMemsetAsync(accum, 0, (WS_FLOATS - OFF_ACCUM) * sizeof(float), stream);

  k0_transpose<<<1024, 256, 0, stream>>>(x, xT);
  k1_qkv<<<dim3(392, 2), 256, 0, stream>>>(xT, wq, wk, wv, qkv);
  k2_stats<<<256, 256, 0, stream>>>(qkv, g_q, b_q, g_k, b_k, g_v, b_v, qkvsc, qkvsh);
  k3_scores<<<dim3(14, 8, 8), 256, 0, stream>>>(qkv, qkvsc, qkvsh, k_rel, krb, accum);
  k4_bn<<<1, 64, 0, stream>>>(accum, g_kr, g_qk, bnpar);
  k5_attn<<<dim3(14, 8, 8), 256, 0, stream>>>(qkv, qkvsc, qkvsh, krb, bnpar, v_rel, sv_ws, sve_ws);
  k6_stats2<<<256, 256, 0, stream>>>(sv_ws, sve_ws, g_sv, b_sv, g_sve, b_sve, bnpar2);
  k7_out<<<1024, 256, 0, stream>>>(sv_ws, sve_ws, bnpar2, (float*)d_out);
}

// Round 13
// 206.767 us; speedup vs baseline: 1.2736x; 1.0146x over previous
//
#include <hip/hip_runtime.h>

#define EPSV 1e-5f

// problem sizes
#define NB   8
#define CC   128
#define HH   56
#define WW   56
#define HW   3136      // 56*56
#define NHW  25088     // 8*3136
#define GG   8

// workspace offsets (in floats)
// xT ([b][c][w][h]) aliases SV region (dead after K1; sv first written by K5).
// qr path removed: qr is constant along the softmax axis and softmax(a+c)=
// softmax(a), so qr and the BN shifts of qr/kr/qk cancel exactly.
#define OFF_QKV      0            // [256][NHW]  (o-major; spatial = w*56+h)
#define OFF_SV       6422528      // [128][NHW]  (ch-major, ch = g*16+c; spatial w*56+h)
#define OFF_SVE      9633792      // [128][NHW]
#define OFF_KRB      12845056     // [b][g][w][j] = [8][8][56][56]
#define OFF_QKVSC    13045760     // [256] scale
#define OFF_QKVSH    13046016     // [256] shift
#define OFF_BNPAR    13046272     // [16]: kr_sc[8], qk_sc[8]
#define OFF_BNPAR2   13046288     // [512]: sv_sc[128], sv_sh[128], sve_sc[128], sve_sh[128]
#define OFF_ACCUM    13046816     // [32 x 32]: kr_s, kr_s2, qk_s, qk_s2 (128B-padded lines)
#define WS_FLOATS    13047840

// padded accumulator slot: one 128B cache line per counter
#define ACC_IDX(u, g) (((u) * 8 + (g)) * 32)

// ---------------------------------------------------------------------------
// K0: transpose x[b][c][h][w] -> xT[b][c][w][h]. One (b,c) plane per block.
// ---------------------------------------------------------------------------
__global__ __launch_bounds__(256) void k0_transpose(
    const float* __restrict__ x, float* __restrict__ xT) {
  __shared__ float t[56][60];
  const int c = blockIdx.x & 127, b = blockIdx.x >> 7;
  const size_t base = ((size_t)b * 128 + c) * HW;
  const int tid = threadIdx.x;
  for (int f = tid; f < 784; f += 256) {
    int e = f * 4;
    int h = e / 56, w = e - h * 56;          // w multiple of 4
    float4 v = *(const float4*)(x + base + e);
    *(float4*)&t[h][w] = v;
  }
  __syncthreads();
  for (int f = tid; f < 784; f += 256) {
    int e = f * 4;
    int w = e / 56, h0 = e - w * 56;         // h0 multiple of 4
    float4 v = make_float4(t[h0][w], t[h0 + 1][w], t[h0 + 2][w], t[h0 + 3][w]);
    *(float4*)(xT + base + w * 56 + h0) = v;
  }
}

// ---------------------------------------------------------------------------
// K1: QKV 1x1-conv GEMM. out[o][p] = sum_k W[o][k] * xT[b][k][s'], s' = w*56+h.
// ---------------------------------------------------------------------------
__global__ __launch_bounds__(256) void k1_qkv(
    const float* __restrict__ x, const float* __restrict__ wq,
    const float* __restrict__ wk, const float* __restrict__ wv,
    float* __restrict__ qkv) {
  __shared__ float Wc[32][132];   // [k][o_local], padded row (528B, float4-aligned)
  __shared__ float Xc[32][64];    // [k][p_local]
  const int p0 = blockIdx.x * 64;
  const int o0 = blockIdx.y * 128;
  const int tid = threadIdx.x;
  const int io = tid & 15, ip = tid >> 4;
  const int bb = p0 / HW;
  const int s0 = p0 - bb * HW;    // 64 | 3136, tile never crosses b

  float acc[8][4];
#pragma unroll
  for (int r = 0; r < 8; ++r)
#pragma unroll
    for (int s = 0; s < 4; ++s) acc[r][s] = 0.f;

  for (int kc = 0; kc < 128; kc += 32) {
    if (kc) __syncthreads();
#pragma unroll
    for (int r = 0; r < 4; ++r) {
      int f = tid + 256 * r;            // 1024 float4 slots
      int ol = f >> 3;
      int kq = (f & 7) * 4;
      int o = o0 + ol;
      const float* wsrc = (o < 64) ? (wq + (size_t)o * 128)
                        : (o < 128) ? (wk + (size_t)(o - 64) * 128)
                                    : (wv + (size_t)(o - 128) * 128);
      float4 w4 = *(const float4*)(wsrc + kc + kq);
      Wc[kq + 0][ol] = w4.x; Wc[kq + 1][ol] = w4.y;
      Wc[kq + 2][ol] = w4.z; Wc[kq + 3][ol] = w4.w;
    }
#pragma unroll
    for (int r = 0; r < 2; ++r) {
      int f = tid + 256 * r;            // 512 float4 slots
      int k = f >> 4;
      int pq = (f & 15) * 4;
      float4 x4 = *(const float4*)(x + (size_t)(bb * 128 + kc + k) * HW + s0 + pq);
      *(float4*)&Xc[k][pq] = x4;
    }
    __syncthreads();
#pragma unroll
    for (int k = 0; k < 32; ++k) {
      float4 xv = *(const float4*)&Xc[k][ip * 4];
      float4 wa = *(const float4*)&Wc[k][io * 8];
      float4 wb = *(const float4*)&Wc[k][io * 8 + 4];
      float wr[8] = {wa.x, wa.y, wa.z, wa.w, wb.x, wb.y, wb.z, wb.w};
      float xr[4] = {xv.x, xv.y, xv.z, xv.w};
#pragma unroll
      for (int r = 0; r < 8; ++r)
#pragma unroll
        for (int s = 0; s < 4; ++s)
          acc[r][s] = fmaf(wr[r], xr[s], acc[r][s]);
    }
  }
#pragma unroll
  for (int r = 0; r < 8; ++r) {
    float4 o4 = make_float4(acc[r][0], acc[r][1], acc[r][2], acc[r][3]);
    *(float4*)(qkv + (size_t)(o0 + io * 8 + r) * NHW + p0 + ip * 4) = o4;
  }
}

// ---------------------------------------------------------------------------
// K2: per-channel BN stats for q/k/v -> scale/shift. One block per channel.
// ---------------------------------------------------------------------------
__global__ __launch_bounds__(256) void k2_stats(
    const float* __restrict__ qkv,
    const float* __restrict__ g_q, const float* __restrict__ b_q,
    const float* __restrict__ g_k, const float* __restrict__ b_k,
    const float* __restrict__ g_v, const float* __restrict__ b_v,
    float* __restrict__ sc_out, float* __restrict__ sh_out) {
  const int o = blockIdx.x;
  const float4* p = (const float4*)(qkv + (size_t)o * NHW);
  float s = 0.f, s2 = 0.f;
  for (int f = threadIdx.x; f < NHW / 4; f += 256) {
    float4 v = p[f];
    s  += v.x + v.y + v.z + v.w;
    s2 += v.x * v.x + v.y * v.y + v.z * v.z + v.w * v.w;
  }
#pragma unroll
  for (int off = 32; off > 0; off >>= 1) {
    s  += __shfl_down(s, off);
    s2 += __shfl_down(s2, off);
  }
  __shared__ float ls[8];
  int wv_ = threadIdx.x >> 6, ln = threadIdx.x & 63;
  if (ln == 0) { ls[wv_] = s; ls[4 + wv_] = s2; }
  __syncthreads();
  if (threadIdx.x == 0) {
    s  = ls[0] + ls[1] + ls[2] + ls[3];
    s2 = ls[4] + ls[5] + ls[6] + ls[7];
    float mean = s / (float)NHW;
    float var  = s2 / (float)NHW - mean * mean;
    float g, b;
    if (o < 64)       { g = g_q[o];       b = b_q[o]; }
    else if (o < 128) { g = g_k[o - 64];  b = b_k[o - 64]; }
    else              { g = g_v[o - 128]; b = b_v[o - 128]; }
    float sc = g * rsqrtf(var + EPSV);
    sc_out[o] = sc;
    sh_out[o] = b - mean * sc;
  }
}

// ---------------------------------------------------------------------------
// K3: kr base (raw, pre-BN) + kr/qk sum/sumsq per group. Padded-line atomics.
// QK inner loop uses explicit float4 LDS reads (ds_read_b128).
// ---------------------------------------------------------------------------
__global__ __launch_bounds__(256) void k3_scores(
    const float* __restrict__ qkv,
    const float* __restrict__ qsc, const float* __restrict__ qsh,
    const float* __restrict__ k_rel,
    float* __restrict__ krb, float* __restrict__ accum) {
  __shared__ float qn[8][4][56];   // [c][wl][h]
  __shared__ float kn[8][4][56];
  __shared__ float red[4][4];
  const int w0 = blockIdx.x * 4, g = blockIdx.y, b = blockIdx.z;
  const int tid = threadIdx.x;

  for (int f = tid; f < 896; f += 256) {
    int isK = f >= 448;
    int idx = f - 448 * isK;
    int c = idx / 56, r = idx - c * 56;
    int wl = r / 14, hq = (r - wl * 14) * 4;
    int o = g * 8 + c + 64 * isK;
    float4 v = *(const float4*)(qkv + (size_t)o * NHW + b * HW + (w0 + wl) * 56 + hq);
    float sc = qsc[o], sh = qsh[o];
    float4 n = make_float4(fmaf(v.x, sc, sh), fmaf(v.y, sc, sh),
                           fmaf(v.z, sc, sh), fmaf(v.w, sc, sh));
    if (isK) *(float4*)&kn[c][wl][hq] = n;
    else     *(float4*)&qn[c][wl][hq] = n;
  }
  __syncthreads();

  float vkr = 0.f, vkr2 = 0.f, vqk = 0.f, vqk2 = 0.f;
  if (tid < 224) {
    const int i = tid % 56, wl = tid / 56;
    float qreg[8];
#pragma unroll
    for (int c = 0; c < 8; ++c) qreg[c] = qn[c][wl][i];
    float krv = 0.f;
#pragma unroll
    for (int c = 0; c < 8; ++c)
      krv = fmaf(kn[c][wl][i], k_rel[c * 56 + i], krv);
    size_t bo = ((size_t)(b * 8 + g) * 56 + w0 + wl) * 56 + i;  // [b][g][w][j]
    krb[bo] = krv;
    vkr = krv; vkr2 = krv * krv;
#pragma unroll
    for (int jq = 0; jq < 14; ++jq) {
      float s0 = 0.f, s1 = 0.f, s2 = 0.f, s3 = 0.f;
#pragma unroll
      for (int c = 0; c < 8; ++c) {
        float4 k4 = *(const float4*)&kn[c][wl][jq * 4];
        float qc = qreg[c];
        s0 = fmaf(qc, k4.x, s0); s1 = fmaf(qc, k4.y, s1);
        s2 = fmaf(qc, k4.z, s2); s3 = fmaf(qc, k4.w, s3);
      }
      vqk  += s0 + s1 + s2 + s3;
      vqk2 += s0 * s0 + s1 * s1 + s2 * s2 + s3 * s3;
    }
  }
  float vals[4] = {vkr, vkr2, vqk, vqk2};
#pragma unroll
  for (int u = 0; u < 4; ++u)
#pragma unroll
    for (int off = 32; off > 0; off >>= 1) vals[u] += __shfl_down(vals[u], off);
  int wv_ = tid >> 6, ln = tid & 63;
  if (ln == 0)
#pragma unroll
    for (int u = 0; u < 4; ++u) red[wv_][u] = vals[u];
  __syncthreads();
  if (tid == 0) {
#pragma unroll
    for (int u = 0; u < 4; ++u)
      atomicAdd(&accum[ACC_IDX(u, g)], red[0][u] + red[1][u] + red[2][u] + red[3][u]);
  }
}

// ---------------------------------------------------------------------------
// K4: fold stats -> per-group scales (shifts cancel in softmax).
// ---------------------------------------------------------------------------
__global__ void k4_bn(
    const float* __restrict__ accum,
    const float* __restrict__ g_kr, const float* __restrict__ g_qk,
    float* __restrict__ bnpar) {
  int g = threadIdx.x;
  if (g >= 8) return;
  const float inv1 = 1.f / 25088.f;      // kr count (N*H*W)
  const float inv2 = 1.f / 1404928.f;    // qk count (N*H*H*W)
  float m, v;
  m = accum[ACC_IDX(0, g)] * inv1; v = accum[ACC_IDX(1, g)] * inv1 - m * m;
  bnpar[g]     = g_kr[g] * rsqrtf(v + EPSV);
  m = accum[ACC_IDX(2, g)] * inv2; v = accum[ACC_IDX(3, g)] * inv2 - m * m;
  bnpar[8 + g] = g_qk[g] * rsqrtf(v + EPSV);
}

// ---------------------------------------------------------------------------
// K5: attention. Block = (w-tile, g, b). Thread (i, wl) owns one softmax row.
// All inner-loop LDS reads are explicit float4 (ds_read_b128): 2240 scalar
// reads/thread -> ~574 vector reads (R10 diagnosis: LDS-issue-bound, 57us).
// srow kept as float4[14] with static indexing only (stays in registers).
// ---------------------------------------------------------------------------
__global__ __launch_bounds__(256) void k5_attn(
    const float* __restrict__ qkv,
    const float* __restrict__ qsc, const float* __restrict__ qsh,
    const float* __restrict__ krb, const float* __restrict__ bnpar,
    const float* __restrict__ v_rel,
    float* __restrict__ sv_ws, float* __restrict__ sve_ws) {
  __shared__ float qn[8][4][56];    // [c][wl][h]
  __shared__ float kn[8][4][56];
  __shared__ float vn[16][4][56];
  __shared__ float krn[4][56];
  __shared__ float vr[16][56];
  const int w0 = blockIdx.x * 4, g = blockIdx.y, b = blockIdx.z;
  const int tid = threadIdx.x;

  for (int f = tid; f < 1792; f += 256) {
    int c, o; float* dst;
    int idx = f;
    if (f < 448)      { c = idx / 56;                      o = g * 8 + c;         dst = (float*)qn + c * 224; }
    else if (f < 896) { idx = f - 448; c = idx / 56;       o = 64 + g * 8 + c;    dst = (float*)kn + c * 224; }
    else              { idx = f - 896; c = idx / 56;       o = 128 + g * 16 + c;  dst = (float*)vn + c * 224; }
    int r = idx - c * 56;
    int wl = r / 14, hq = (r - wl * 14) * 4;
    float4 v = *(const float4*)(qkv + (size_t)o * NHW + b * HW + (w0 + wl) * 56 + hq);
    float sc = qsc[o], sh = qsh[o];
    float4 n = make_float4(fmaf(v.x, sc, sh), fmaf(v.y, sc, sh),
                           fmaf(v.z, sc, sh), fmaf(v.w, sc, sh));
    *(float4*)(dst + wl * 56 + hq) = n;
  }
  {
    float kr_sc = bnpar[g];
    if (tid < 224) {
      int i = tid % 56, wl = tid / 56;
      size_t bo = ((size_t)(b * 8 + g) * 56 + w0 + wl) * 56 + i;  // [b][g][w][j]
      krn[wl][i] = krb[bo] * kr_sc;    // shift cancels in softmax
    }
  }
  for (int f = tid; f < 896; f += 256) ((float*)vr)[f] = v_rel[f];
  __syncthreads();

  if (tid < 224) {
    const int i = tid % 56, wl = tid / 56;
    float qreg[8];
#pragma unroll
    for (int c = 0; c < 8; ++c) qreg[c] = qn[c][wl][i];
    const float qksc = bnpar[8 + g];

    float4 srow4[14];
    float mx = -3.402823466e38f;
#pragma unroll
    for (int jq = 0; jq < 14; ++jq) {
      float s0 = 0.f, s1 = 0.f, s2 = 0.f, s3 = 0.f;
#pragma unroll
      for (int c = 0; c < 8; ++c) {
        float4 k4 = *(const float4*)&kn[c][wl][jq * 4];
        float qc = qreg[c];
        s0 = fmaf(qc, k4.x, s0); s1 = fmaf(qc, k4.y, s1);
        s2 = fmaf(qc, k4.z, s2); s3 = fmaf(qc, k4.w, s3);
      }
      float4 kr4 = *(const float4*)&krn[wl][jq * 4];
      s0 = fmaf(qksc, s0, kr4.x);
      s1 = fmaf(qksc, s1, kr4.y);
      s2 = fmaf(qksc, s2, kr4.z);
      s3 = fmaf(qksc, s3, kr4.w);
      srow4[jq] = make_float4(s0, s1, s2, s3);
      mx = fmaxf(mx, fmaxf(fmaxf(s0, s1), fmaxf(s2, s3)));
    }
    float sum = 0.f;
#pragma unroll
    for (int jq = 0; jq < 14; ++jq) {
      float4 s = srow4[jq];
      s.x = expf(s.x - mx); s.y = expf(s.y - mx);
      s.z = expf(s.z - mx); s.w = expf(s.w - mx);
      srow4[jq] = s;
      sum += (s.x + s.y) + (s.z + s.w);
    }
    float inv = 1.f / sum;

    float sv[16], sve[16];
#pragma unroll
    for (int c = 0; c < 16; ++c) { sv[c] = 0.f; sve[c] = 0.f; }
#pragma unroll
    for (int jq = 0; jq < 14; ++jq) {
      float4 p = srow4[jq];
#pragma unroll
      for (int c = 0; c < 16; ++c) {
        float4 v4 = *(const float4*)&vn[c][wl][jq * 4];
        float4 e4 = *(const float4*)&vr[c][jq * 4];
        sv[c]  = fmaf(p.x, v4.x, fmaf(p.y, v4.y, fmaf(p.z, v4.z, fmaf(p.w, v4.w, sv[c]))));
        sve[c] = fmaf(p.x, e4.x, fmaf(p.y, e4.y, fmaf(p.z, e4.z, fmaf(p.w, e4.w, sve[c]))));
      }
    }
#pragma unroll
    for (int c = 0; c < 16; ++c) {
      size_t base = (size_t)(g * 16 + c) * NHW + b * HW + (w0 + wl) * 56 + i;
      sv_ws[base]  = sv[c]  * inv;   // contiguous across consecutive tid (i)
      sve_ws[base] = sve[c] * inv;
    }
  }
}

// ---------------------------------------------------------------------------
// K6: per-channel BN stats for sv (blocks 0-127) and sve (blocks 128-255),
// folded directly into bnpar2.
// ---------------------------------------------------------------------------
__global__ __launch_bounds__(256) void k6_stats2(
    const float* __restrict__ sv_ws, const float* __restrict__ sve_ws,
    const float* __restrict__ g_sv, const float* __restrict__ b_sv,
    const float* __restrict__ g_sve, const float* __restrict__ b_sve,
    float* __restrict__ bnpar2) {
  const int cb = blockIdx.x;
  const int ch = cb & 127;
  const float* src = (cb < 128) ? sv_ws : sve_ws;
  const float4* p = (const float4*)(src + (size_t)ch * NHW);
  float s = 0.f, s2 = 0.f;
  for (int f = threadIdx.x; f < NHW / 4; f += 256) {
    float4 v = p[f];
    s  += v.x + v.y + v.z + v.w;
    s2 += v.x * v.x + v.y * v.y + v.z * v.z + v.w * v.w;
  }
#pragma unroll
  for (int off = 32; off > 0; off >>= 1) {
    s  += __shfl_down(s, off);
    s2 += __shfl_down(s2, off);
  }
  __shared__ float ls[8];
  int wv_ = threadIdx.x >> 6, ln = threadIdx.x & 63;
  if (ln == 0) { ls[wv_] = s; ls[4 + wv_] = s2; }
  __syncthreads();
  if (threadIdx.x == 0) {
    s  = ls[0] + ls[1] + ls[2] + ls[3];
    s2 = ls[4] + ls[5] + ls[6] + ls[7];
    float m = s / (float)NHW;
    float var = s2 / (float)NHW - m * m;
    float gm = (cb < 128) ? g_sv[ch] : g_sve[ch];
    float bt = (cb < 128) ? b_sv[ch] : b_sve[ch];
    float sc = gm * rsqrtf(var + EPSV);
    int off = (cb < 128) ? 0 : 256;
    bnpar2[off + ch] = sc;
    bnpar2[off + 128 + ch] = bt - m * sc;
  }
}

// ---------------------------------------------------------------------------
// K7: fused double-BN + transpose back: out[b][ch][h][w] from
// sv/sve[ch][b][w][h]. One (ch,b) plane per block, LDS-tiled.
// ---------------------------------------------------------------------------
__global__ __launch_bounds__(256) void k7_out(
    const float* __restrict__ sv_ws, const float* __restrict__ sve_ws,
    const float* __restrict__ bnpar2, float* __restrict__ out) {
  __shared__ float t[56][60];
  const int ch = blockIdx.x & 127, b = blockIdx.x >> 7;
  const int tid = threadIdx.x;
  const float asc = bnpar2[ch], ash = bnpar2[128 + ch];
  const float esc = bnpar2[256 + ch], esh = bnpar2[384 + ch];
  const size_t pin = ((size_t)ch * NB + b) * HW;
  for (int f = tid; f < 784; f += 256) {
    int e = f * 4;
    int w = e / 56, h = e - w * 56;          // h multiple of 4
    float4 a  = *(const float4*)(sv_ws + pin + e);
    float4 c4 = *(const float4*)(sve_ws + pin + e);
    float4 o4;
    o4.x = fmaf(a.x, asc, ash) + fmaf(c4.x, esc, esh);
    o4.y = fmaf(a.y, asc, ash) + fmaf(c4.y, esc, esh);
    o4.z = fmaf(a.z, asc, ash) + fmaf(c4.z, esc, esh);
    o4.w = fmaf(a.w, asc, ash) + fmaf(c4.w, esc, esh);
    *(float4*)&t[w][h] = o4;
  }
  __syncthreads();
  const size_t pout = ((size_t)b * 128 + ch) * HW;
  for (int f = tid; f < 784; f += 256) {
    int e = f * 4;
    int h = e / 56, w0 = e - h * 56;         // w0 multiple of 4
    float4 o4 = make_float4(t[w0][h], t[w0 + 1][h], t[w0 + 2][h], t[w0 + 3][h]);
    *(float4*)(out + pout + h * 56 + w0) = o4;
  }
}

// ---------------------------------------------------------------------------
extern "C" void kernel_launch(void* const* d_in, const int* in_sizes, int n_in,
                              void* d_out, int out_size, void* d_ws, size_t ws_size,
                              hipStream_t stream) {
  (void)in_sizes; (void)n_in; (void)out_size;
  if (ws_size < (size_t)WS_FLOATS * sizeof(float)) return;  // diagnostic guard

  const float* x     = (const float*)d_in[0];
  const float* wq    = (const float*)d_in[1];
  const float* wk    = (const float*)d_in[2];
  const float* wv    = (const float*)d_in[3];
  const float* k_rel = (const float*)d_in[5];
  const float* v_rel = (const float*)d_in[6];
  const float* g_q   = (const float*)d_in[7];
  const float* b_q   = (const float*)d_in[8];
  const float* g_k   = (const float*)d_in[9];
  const float* b_k   = (const float*)d_in[10];
  const float* g_v   = (const float*)d_in[11];
  const float* b_v   = (const float*)d_in[12];
  const float* g_kr  = (const float*)d_in[15];
  const float* g_qk  = (const float*)d_in[17];
  const float* g_sv  = (const float*)d_in[19];
  const float* b_sv  = (const float*)d_in[20];
  const float* g_sve = (const float*)d_in[21];
  const float* b_sve = (const float*)d_in[22];
  // q_rel(4), g_qr(13), b_qr(14), b_kr(16), b_qk(18) unused: cancel in softmax.

  float* ws     = (float*)d_ws;
  float* qkv    = ws + OFF_QKV;
  float* sv_ws  = ws + OFF_SV;
  float* sve_ws = ws + OFF_SVE;
  float* xT     = ws + OFF_SV;      // aliases SV region (dead after K1)
  float* krb    = ws + OFF_KRB;
  float* qkvsc  = ws + OFF_QKVSC;
  float* qkvsh  = ws + OFF_QKVSH;
  float* bnpar  = ws + OFF_BNPAR;
  float* bnpar2 = ws + OFF_BNPAR2;
  float* accum  = ws + OFF_ACCUM;

  hipMemsetAsync(accum, 0, (WS_FLOATS - OFF_ACCUM) * sizeof(float), stream);

  k0_transpose<<<1024, 256, 0, stream>>>(x, xT);
  k1_qkv<<<dim3(392, 2), 256, 0, stream>>>(xT, wq, wk, wv, qkv);
  k2_stats<<<256, 256, 0, stream>>>(qkv, g_q, b_q, g_k, b_k, g_v, b_v, qkvsc, qkvsh);
  k3_scores<<<dim3(14, 8, 8), 256, 0, stream>>>(qkv, qkvsc, qkvsh, k_rel, krb, accum);
  k4_bn<<<1, 64, 0, stream>>>(accum, g_kr, g_qk, bnpar);
  k5_attn<<<dim3(14, 8, 8), 256, 0, stream>>>(qkv, qkvsc, qkvsh, krb, bnpar, v_rel, sv_ws, sve_ws);
  k6_stats2<<<256, 256, 0, stream>>>(sv_ws, sve_ws, g_sv, b_sv, g_sve, b_sve, bnpar2);
  k7_out<<<1024, 256, 0, stream>>>(sv_ws, sve_ws, bnpar2, (float*)d_out);
}